// Round 3
// baseline (636.961 us; speedup 1.0000x reference)
//
#include <hip/hip_runtime.h>
#include <cstdint>
#include <cstddef>

// Paged GQA flash-decode attention, fp32, split-KV two-pass.
// R6 == R5 resubmit (previous round died on container acquire, no signal).
// All-register K/V streaming. No LDS staging, no glds, no barriers in
// the main loop. btab chunk cached in LDS (lgkmcnt) so the vmcnt stream is
// pure K/V and the compiler emits counted (non-drain) waits: QK waits only
// K's 8 loads, PV waits only V's 16. K loads are sector-perfect (16 rows x
// contiguous 64B per instruction via 16-float-strided fragments); V loads
// are contiguous 512B per token. K(i+1)/V(i+1) issued mid-iteration.

#define NB 16
#define NH 32
#define HD 128
#define NT 4096
#define NKVH 8
#define NG 4
#define NSPLIT 16
#define TILE_T 16
#define NWAVE 4
#define PART_STRIDE 520          // o[4][128] + m[4] + l[4]
#define SCALE_F 0.08838834764831845f
#define KVROW (NKVH * HD)        // floats per page row = 1024

__device__ __forceinline__ void fence_sched() { __asm__ volatile("" ::: "memory"); }

__global__ __launch_bounds__(256, 2) void attn_partial_kernel(
    const float* __restrict__ q,
    const float* __restrict__ kc,
    const float* __restrict__ vc,
    const int*   __restrict__ kv_lens,
    const int*   __restrict__ btab,
    float*       __restrict__ part)
{
    __shared__ int bt_lds[256];                               // chunk page ids
    __shared__ __align__(16) float p_lds[NWAVE][TILE_T][NG];  // 1 KB
    __shared__ __align__(16) float a_lds[NWAVE][NG];
    __shared__ __align__(16) float ml_lds[NWAVE][NG][2];
    __shared__ __align__(16) float o_lds[NWAVE][NG][HD];      // 8 KB
    // ~10.5 KB LDS; occupancy VGPR-limited (2 waves/SIMD)

    const int bid = blockIdx.x;                 // (b*NKVH + kvh)*NSPLIT + c
    const int c   = bid % NSPLIT;
    const int kvh = (bid / NSPLIT) % NKVH;
    const int b   = bid / (NSPLIT * NKVH);
    const int tid  = threadIdx.x;
    const int w    = tid >> 6;
    const int lane = tid & 63;

    const int kv_len = kv_lens[b];
    const int clen = (kv_len + NSPLIT - 1) / NSPLIT;   // <= 256
    const int t0c = c * clen;
    const int t1c = min(t0c + clen, kv_len);

    float* pb = part + (size_t)bid * PART_STRIDE;

    if (t0c >= kv_len) {       // only when kv_len < NSPLIT (block-uniform)
        for (int i = tid; i < PART_STRIDE; i += 256)
            pb[i] = (i >= 512 && i < 516) ? -1e30f : 0.0f;
        return;
    }

    // cache this chunk's page ids in LDS (reads below are lgkm, not vmcnt)
    const int nchunk = t1c - t0c;
    for (int i = tid; i < nchunk; i += 256)
        bt_lds[i] = btab[b * NT + t0c + i];
    __syncthreads();

    // lane roles: lane = (lt:4)(sg:2). lt = token in 16-tile, sg = strided
    // quarter of D: floats f = sg*4 + 16*j + e  (j=0..7, e=0..3)
    const int lt = lane >> 2;
    const int sg = lane & 3;

    // q fragments: 4 heads x 8 float4, strided selection, pre-scaled (128 VGPR)
    float4 qreg[NG][8];
    {
        const float* qb = q + ((size_t)(b * NH + kvh * NG)) * HD + sg * 4;
        #pragma unroll
        for (int g = 0; g < NG; ++g) {
            #pragma unroll
            for (int j = 0; j < 8; ++j) {
                float4 t = *(const float4*)(qb + g * HD + j * 16);
                qreg[g][j] = make_float4(t.x * SCALE_F, t.y * SCALE_F,
                                         t.z * SCALE_F, t.w * SCALE_F);
            }
        }
    }

    const float* kbase = kc + (size_t)kvh * HD + sg * 4;   // + row*KVROW + 16j
    const float* vbase = vc + (size_t)kvh * HD + 2 * lane; // + row*KVROW

    float m_g = -1e30f, l_g = 0.0f;
    float o0x=0,o0y=0,o1x=0,o1y=0,o2x=0,o2y=0,o3x=0,o3y=0;

    float4 kreg[8];        // current K tile fragment (32 VGPR)
    float2 vreg[TILE_T];   // current V tile (32 VGPR)

    int t0 = t0c + w * TILE_T;

    if (t0 < t1c) {
        // ---- prologue: issue tile-0 K and V
        int tokK = t0 + lt;
        fence_sched();
        if (tokK < t1c) {
            const float* kp = kbase + (size_t)bt_lds[tokK - t0c] * KVROW;
            #pragma unroll
            for (int j = 0; j < 8; ++j)
                kreg[j] = *(const float4*)(kp + j * 16);
        } else {
            #pragma unroll
            for (int j = 0; j < 8; ++j)
                kreg[j] = make_float4(0.f, 0.f, 0.f, 0.f);
        }
        #pragma unroll
        for (int t = 0; t < TILE_T; ++t) {
            int tok = t0 + t;
            vreg[t] = make_float2(0.f, 0.f);
            if (tok < t1c)
                vreg[t] = *(const float2*)(vbase + (size_t)bt_lds[tok - t0c] * KVROW);
        }
        fence_sched();
    }

    for (; t0 < t1c; t0 += NWAVE * TILE_T) {
        const int t0n = t0 + NWAVE * TILE_T;
        const bool has_next = (t0n < t1c);

        // ---- QK: lane dots its strided quarter for all 4 heads
        // (compiler waits only the 8 K loads here; V's 16 stay in flight)
        float s0 = 0, s1 = 0, s2 = 0, s3 = 0;
        #pragma unroll
        for (int j = 0; j < 8; ++j) {
            float4 kk = kreg[j];
            float4 q0 = qreg[0][j], q1 = qreg[1][j], q2 = qreg[2][j], q3 = qreg[3][j];
            s0 = fmaf(kk.x,q0.x,fmaf(kk.y,q0.y,fmaf(kk.z,q0.z,fmaf(kk.w,q0.w,s0))));
            s1 = fmaf(kk.x,q1.x,fmaf(kk.y,q1.y,fmaf(kk.z,q1.z,fmaf(kk.w,q1.w,s1))));
            s2 = fmaf(kk.x,q2.x,fmaf(kk.y,q2.y,fmaf(kk.z,q2.z,fmaf(kk.w,q2.w,s2))));
            s3 = fmaf(kk.x,q3.x,fmaf(kk.y,q3.y,fmaf(kk.z,q3.z,fmaf(kk.w,q3.w,s3))));
        }
        s0 += __shfl_xor(s0, 1); s0 += __shfl_xor(s0, 2);
        s1 += __shfl_xor(s1, 1); s1 += __shfl_xor(s1, 2);
        s2 += __shfl_xor(s2, 1); s2 += __shfl_xor(s2, 2);
        s3 += __shfl_xor(s3, 1); s3 += __shfl_xor(s3, 2);
        float s = (sg == 0) ? s0 : (sg == 1) ? s1 : (sg == 2) ? s2 : s3;
        if (t0 + lt >= t1c) s = -1e30f;

        // ---- issue K(i+1) into kreg (kreg consumed above; WAR on regs ok)
        if (has_next) {
            int tokK = t0n + lt;
            fence_sched();
            if (tokK < t1c) {
                const float* kp = kbase + (size_t)bt_lds[tokK - t0c] * KVROW;
                #pragma unroll
                for (int j = 0; j < 8; ++j)
                    kreg[j] = *(const float4*)(kp + j * 16);
            } else {
                #pragma unroll
                for (int j = 0; j < 8; ++j)
                    kreg[j] = make_float4(0.f, 0.f, 0.f, 0.f);
            }
            fence_sched();
        }

        // ---- online softmax over the 16 tokens per head (lanes xor 4..32)
        float tmax = s;
        #pragma unroll
        for (int off = 4; off < 64; off <<= 1)
            tmax = fmaxf(tmax, __shfl_xor(tmax, off));
        float m_new = fmaxf(m_g, tmax);
        float alpha = __expf(m_g - m_new);
        float p     = __expf(s - m_new);
        float tsum  = p;
        #pragma unroll
        for (int off = 4; off < 64; off <<= 1)
            tsum += __shfl_xor(tsum, off);
        l_g = l_g * alpha + tsum;
        m_g = m_new;

        p_lds[w][lt][sg] = p;                 // 64 distinct addrs, conflict-free
        if (lt == 0) a_lds[w][sg] = alpha;

        // ---- PV: lane owns d-pair 2*lane; p broadcast from tiny LDS
        // (compiler waits only the 16 V loads here)
        float4 aa = *(const float4*)&a_lds[w][0];
        o0x *= aa.x; o0y *= aa.x; o1x *= aa.y; o1y *= aa.y;
        o2x *= aa.z; o2y *= aa.z; o3x *= aa.w; o3y *= aa.w;
        #pragma unroll
        for (int t = 0; t < TILE_T; ++t) {
            float4 pp = *(const float4*)&p_lds[w][t][0];
            float2 vv = vreg[t];
            o0x = fmaf(pp.x, vv.x, o0x); o0y = fmaf(pp.x, vv.y, o0y);
            o1x = fmaf(pp.y, vv.x, o1x); o1y = fmaf(pp.y, vv.y, o1y);
            o2x = fmaf(pp.z, vv.x, o2x); o2y = fmaf(pp.z, vv.y, o2y);
            o3x = fmaf(pp.w, vv.x, o3x); o3y = fmaf(pp.w, vv.y, o3y);
        }

        // ---- issue V(i+1) into vreg (vreg consumed above)
        if (has_next) {
            fence_sched();
            #pragma unroll
            for (int t = 0; t < TILE_T; ++t) {
                int tok = t0n + t;
                float2 nv = make_float2(0.f, 0.f);
                if (tok < t1c)
                    nv = *(const float2*)(vbase + (size_t)bt_lds[tok - t0c] * KVROW);
                vreg[t] = nv;
            }
            fence_sched();
        }
    }

    // ---- cross-wave combine within block
    {
        *(float2*)&o_lds[w][0][2 * lane] = make_float2(o0x, o0y);
        *(float2*)&o_lds[w][1][2 * lane] = make_float2(o1x, o1y);
        *(float2*)&o_lds[w][2][2 * lane] = make_float2(o2x, o2y);
        *(float2*)&o_lds[w][3][2 * lane] = make_float2(o3x, o3y);
        if (lt == 0) { ml_lds[w][sg][0] = m_g; ml_lds[w][sg][1] = l_g; }
    }
    __syncthreads();

    {
        int g  = tid >> 6;
        int d2 = (tid & 63) * 2;
        float M = fmaxf(fmaxf(ml_lds[0][g][0], ml_lds[1][g][0]),
                        fmaxf(ml_lds[2][g][0], ml_lds[3][g][0]));
        float L = 0.0f, O0 = 0.0f, O1 = 0.0f;
        #pragma unroll
        for (int wv = 0; wv < NWAVE; ++wv) {
            float sc = __expf(ml_lds[wv][g][0] - M);   // idle wave contributes 0
            L  += ml_lds[wv][g][1] * sc;
            O0 += o_lds[wv][g][d2]     * sc;
            O1 += o_lds[wv][g][d2 + 1] * sc;
        }
        pb[g * HD + d2]     = O0;          // unnormalized partial
        pb[g * HD + d2 + 1] = O1;
        if ((tid & 63) == 0) { pb[512 + g] = M; pb[516 + g] = L; }
    }
}

__global__ __launch_bounds__(256) void attn_combine_kernel(
    const float* __restrict__ part, float* __restrict__ out)
{
    const int bid = blockIdx.x;        // b*NKVH + kvh
    const int tid = threadIdx.x;
    const int g  = tid >> 6;
    const int d2 = (tid & 63) * 2;
    const int b   = bid / NKVH;
    const int kvh = bid % NKVH;
    const float* pb = part + (size_t)bid * NSPLIT * PART_STRIDE;

    float M = -1e30f;
    #pragma unroll
    for (int cc = 0; cc < NSPLIT; ++cc)
        M = fmaxf(M, pb[cc * PART_STRIDE + 512 + g]);
    float L = 0.0f, O0 = 0.0f, O1 = 0.0f;
    #pragma unroll
    for (int cc = 0; cc < NSPLIT; ++cc) {
        float mc = pb[cc * PART_STRIDE + 512 + g];
        float sc = __expf(mc - M);                    // empty chunk -> 0
        L  += pb[cc * PART_STRIDE + 516 + g] * sc;
        O0 += pb[cc * PART_STRIDE + g * HD + d2]     * sc;
        O1 += pb[cc * PART_STRIDE + g * HD + d2 + 1] * sc;
    }
    float inv = 1.0f / L;                             // chunk 0 non-empty -> L > 0
    const int h = kvh * NG + g;
    out[((size_t)b * NH + h) * HD + d2]     = O0 * inv;
    out[((size_t)b * NH + h) * HD + d2 + 1] = O1 * inv;
}

extern "C" void kernel_launch(void* const* d_in, const int* in_sizes, int n_in,
                              void* d_out, int out_size, void* d_ws, size_t ws_size,
                              hipStream_t stream)
{
    const float* q   = (const float*)d_in[0];
    const float* kc  = (const float*)d_in[1];
    const float* vc  = (const float*)d_in[2];
    const int*   kvl = (const int*)d_in[3];
    const int*   bt  = (const int*)d_in[4];
    float* part = (float*)d_ws;   // 2048 * 520 * 4 B = 4.26 MB of ws used

    attn_partial_kernel<<<NB * NKVH * NSPLIT, 256, 0, stream>>>(q, kc, vc, kvl, bt, part);
    attn_combine_kernel<<<NB * NKVH, 256, 0, stream>>>(part, (float*)d_out);
}

// Round 4
// 458.269 us; speedup vs baseline: 1.3899x; 1.3899x over previous
//
#include <hip/hip_runtime.h>
#include <cstdint>
#include <cstddef>

// Paged GQA flash-decode attention, fp32, split-KV two-pass.
// R7: R5/R6 streaming structure with the spill removed. rocprof showed
// VGPR_Count=128 vs ~210 demand -> 146 MB scratch writes, VALUBusy 5%.
// Fix: q lives in LDS (2 KB/block, broadcast reads), not 128 VGPRs.
// An opaque per-iteration offset (asm "+v") stops LICM from hoisting the
// q_lds reads back into registers. Everything else unchanged: K/V stream
// straight to VGPRs, btab cached in LDS so vmcnt queue is pure K/V and
// the compiler emits counted (non-drain) waits; no barriers in the loop.

#define NB 16
#define NH 32
#define HD 128
#define NT 4096
#define NKVH 8
#define NG 4
#define NSPLIT 16
#define TILE_T 16
#define NWAVE 4
#define PART_STRIDE 520          // o[4][128] + m[4] + l[4]
#define SCALE_F 0.08838834764831845f
#define KVROW (NKVH * HD)        // floats per page row = 1024

__device__ __forceinline__ void fence_sched() { __asm__ volatile("" ::: "memory"); }

__global__ __launch_bounds__(256, 2) void attn_partial_kernel(
    const float* __restrict__ q,
    const float* __restrict__ kc,
    const float* __restrict__ vc,
    const int*   __restrict__ kv_lens,
    const int*   __restrict__ btab,
    float*       __restrict__ part)
{
    __shared__ int bt_lds[256];                               // chunk page ids
    __shared__ __align__(16) float q_lds[NG * HD];            // 2 KB, pre-scaled
    __shared__ __align__(16) float p_lds[NWAVE][TILE_T][NG];  // 1 KB
    __shared__ __align__(16) float a_lds[NWAVE][NG];
    __shared__ __align__(16) float ml_lds[NWAVE][NG][2];
    __shared__ __align__(16) float o_lds[NWAVE][NG][HD];      // 8 KB
    // ~12.5 KB LDS

    const int bid = blockIdx.x;                 // (b*NKVH + kvh)*NSPLIT + c
    const int c   = bid % NSPLIT;
    const int kvh = (bid / NSPLIT) % NKVH;
    const int b   = bid / (NSPLIT * NKVH);
    const int tid  = threadIdx.x;
    const int w    = tid >> 6;
    const int lane = tid & 63;

    const int kv_len = kv_lens[b];
    const int clen = (kv_len + NSPLIT - 1) / NSPLIT;   // <= 256
    const int t0c = c * clen;
    const int t1c = min(t0c + clen, kv_len);

    float* pb = part + (size_t)bid * PART_STRIDE;

    if (t0c >= kv_len) {       // only when kv_len < NSPLIT (block-uniform)
        for (int i = tid; i < PART_STRIDE; i += 256)
            pb[i] = (i >= 512 && i < 516) ? -1e30f : 0.0f;
        return;
    }

    // stage page ids + scaled q into LDS (one barrier for both)
    const int nchunk = t1c - t0c;
    for (int i = tid; i < nchunk; i += 256)
        bt_lds[i] = btab[b * NT + t0c + i];
    if (tid < NG * HD / 4) {
        const float* qb = q + ((size_t)(b * NH + kvh * NG)) * HD;
        float4 t = *((const float4*)qb + tid);
        *(float4*)&q_lds[tid * 4] = make_float4(t.x * SCALE_F, t.y * SCALE_F,
                                                t.z * SCALE_F, t.w * SCALE_F);
    }
    __syncthreads();

    // lane roles: lane = (lt:4)(sg:2). lt = token in 16-tile, sg = strided
    // quarter of D: floats f = sg*4 + 16*j + e  (j=0..7, e=0..3)
    const int lt = lane >> 2;
    const int sg = lane & 3;

    const float* kbase = kc + (size_t)kvh * HD + sg * 4;   // + row*KVROW + 16j
    const float* vbase = vc + (size_t)kvh * HD + 2 * lane; // + row*KVROW

    float m_g = -1e30f, l_g = 0.0f;
    float o0x=0,o0y=0,o1x=0,o1y=0,o2x=0,o2y=0,o3x=0,o3y=0;

    float4 kreg[8];        // current K tile fragment (32 VGPR)
    float2 vreg[TILE_T];   // current V tile (32 VGPR)

    int t0 = t0c + w * TILE_T;

    if (t0 < t1c) {
        // ---- prologue: issue tile-0 K and V
        int tokK = t0 + lt;
        fence_sched();
        if (tokK < t1c) {
            const float* kp = kbase + (size_t)bt_lds[tokK - t0c] * KVROW;
            #pragma unroll
            for (int j = 0; j < 8; ++j)
                kreg[j] = *(const float4*)(kp + j * 16);
        } else {
            #pragma unroll
            for (int j = 0; j < 8; ++j)
                kreg[j] = make_float4(0.f, 0.f, 0.f, 0.f);
        }
        #pragma unroll
        for (int t = 0; t < TILE_T; ++t) {
            int tok = t0 + t;
            vreg[t] = make_float2(0.f, 0.f);
            if (tok < t1c)
                vreg[t] = *(const float2*)(vbase + (size_t)bt_lds[tok - t0c] * KVROW);
        }
        fence_sched();
    }

    for (; t0 < t1c; t0 += NWAVE * TILE_T) {
        const int t0n = t0 + NWAVE * TILE_T;
        const bool has_next = (t0n < t1c);

        // opaque q_lds offset: stops LICM hoisting the 32 q reads into regs
        int qoff = sg * 4;
        __asm__ volatile("" : "+v"(qoff));
        const float* qp = q_lds + qoff;

        // ---- QK: lane dots its strided quarter for all 4 heads
        // (compiler waits only the 8 K loads here; V's 16 stay in flight)
        float s0 = 0, s1 = 0, s2 = 0, s3 = 0;
        #pragma unroll
        for (int j = 0; j < 8; ++j) {
            float4 kk = kreg[j];
            float4 q0 = *(const float4*)(qp + 0 * HD + j * 16);
            float4 q1 = *(const float4*)(qp + 1 * HD + j * 16);
            float4 q2 = *(const float4*)(qp + 2 * HD + j * 16);
            float4 q3 = *(const float4*)(qp + 3 * HD + j * 16);
            s0 = fmaf(kk.x,q0.x,fmaf(kk.y,q0.y,fmaf(kk.z,q0.z,fmaf(kk.w,q0.w,s0))));
            s1 = fmaf(kk.x,q1.x,fmaf(kk.y,q1.y,fmaf(kk.z,q1.z,fmaf(kk.w,q1.w,s1))));
            s2 = fmaf(kk.x,q2.x,fmaf(kk.y,q2.y,fmaf(kk.z,q2.z,fmaf(kk.w,q2.w,s2))));
            s3 = fmaf(kk.x,q3.x,fmaf(kk.y,q3.y,fmaf(kk.z,q3.z,fmaf(kk.w,q3.w,s3))));
        }
        s0 += __shfl_xor(s0, 1); s0 += __shfl_xor(s0, 2);
        s1 += __shfl_xor(s1, 1); s1 += __shfl_xor(s1, 2);
        s2 += __shfl_xor(s2, 1); s2 += __shfl_xor(s2, 2);
        s3 += __shfl_xor(s3, 1); s3 += __shfl_xor(s3, 2);
        float s = (sg == 0) ? s0 : (sg == 1) ? s1 : (sg == 2) ? s2 : s3;
        if (t0 + lt >= t1c) s = -1e30f;

        // ---- issue K(i+1) into kreg (kreg consumed above; WAR on regs ok)
        if (has_next) {
            int tokK = t0n + lt;
            fence_sched();
            if (tokK < t1c) {
                const float* kp = kbase + (size_t)bt_lds[tokK - t0c] * KVROW;
                #pragma unroll
                for (int j = 0; j < 8; ++j)
                    kreg[j] = *(const float4*)(kp + j * 16);
            } else {
                #pragma unroll
                for (int j = 0; j < 8; ++j)
                    kreg[j] = make_float4(0.f, 0.f, 0.f, 0.f);
            }
            fence_sched();
        }

        // ---- online softmax over the 16 tokens per head (lanes xor 4..32)
        float tmax = s;
        #pragma unroll
        for (int off = 4; off < 64; off <<= 1)
            tmax = fmaxf(tmax, __shfl_xor(tmax, off));
        float m_new = fmaxf(m_g, tmax);
        float alpha = __expf(m_g - m_new);
        float p     = __expf(s - m_new);
        float tsum  = p;
        #pragma unroll
        for (int off = 4; off < 64; off <<= 1)
            tsum += __shfl_xor(tsum, off);
        l_g = l_g * alpha + tsum;
        m_g = m_new;

        p_lds[w][lt][sg] = p;                 // 64 distinct addrs, conflict-free
        if (lt == 0) a_lds[w][sg] = alpha;

        // ---- PV: lane owns d-pair 2*lane; p broadcast from tiny LDS
        // (compiler waits only the 16 V loads here)
        float4 aa = *(const float4*)&a_lds[w][0];
        o0x *= aa.x; o0y *= aa.x; o1x *= aa.y; o1y *= aa.y;
        o2x *= aa.z; o2y *= aa.z; o3x *= aa.w; o3y *= aa.w;
        #pragma unroll
        for (int t = 0; t < TILE_T; ++t) {
            float4 pp = *(const float4*)&p_lds[w][t][0];
            float2 vv = vreg[t];
            o0x = fmaf(pp.x, vv.x, o0x); o0y = fmaf(pp.x, vv.y, o0y);
            o1x = fmaf(pp.y, vv.x, o1x); o1y = fmaf(pp.y, vv.y, o1y);
            o2x = fmaf(pp.z, vv.x, o2x); o2y = fmaf(pp.z, vv.y, o2y);
            o3x = fmaf(pp.w, vv.x, o3x); o3y = fmaf(pp.w, vv.y, o3y);
        }

        // ---- issue V(i+1) into vreg (vreg consumed above)
        if (has_next) {
            fence_sched();
            #pragma unroll
            for (int t = 0; t < TILE_T; ++t) {
                int tok = t0n + t;
                float2 nv = make_float2(0.f, 0.f);
                if (tok < t1c)
                    nv = *(const float2*)(vbase + (size_t)bt_lds[tok - t0c] * KVROW);
                vreg[t] = nv;
            }
            fence_sched();
        }
    }

    // ---- cross-wave combine within block
    {
        *(float2*)&o_lds[w][0][2 * lane] = make_float2(o0x, o0y);
        *(float2*)&o_lds[w][1][2 * lane] = make_float2(o1x, o1y);
        *(float2*)&o_lds[w][2][2 * lane] = make_float2(o2x, o2y);
        *(float2*)&o_lds[w][3][2 * lane] = make_float2(o3x, o3y);
        if (lt == 0) { ml_lds[w][sg][0] = m_g; ml_lds[w][sg][1] = l_g; }
    }
    __syncthreads();

    {
        int g  = tid >> 6;
        int d2 = (tid & 63) * 2;
        float M = fmaxf(fmaxf(ml_lds[0][g][0], ml_lds[1][g][0]),
                        fmaxf(ml_lds[2][g][0], ml_lds[3][g][0]));
        float L = 0.0f, O0 = 0.0f, O1 = 0.0f;
        #pragma unroll
        for (int wv = 0; wv < NWAVE; ++wv) {
            float sc = __expf(ml_lds[wv][g][0] - M);   // idle wave contributes 0
            L  += ml_lds[wv][g][1] * sc;
            O0 += o_lds[wv][g][d2]     * sc;
            O1 += o_lds[wv][g][d2 + 1] * sc;
        }
        pb[g * HD + d2]     = O0;          // unnormalized partial
        pb[g * HD + d2 + 1] = O1;
        if ((tid & 63) == 0) { pb[512 + g] = M; pb[516 + g] = L; }
    }
}

__global__ __launch_bounds__(256) void attn_combine_kernel(
    const float* __restrict__ part, float* __restrict__ out)
{
    const int bid = blockIdx.x;        // b*NKVH + kvh
    const int tid = threadIdx.x;
    const int g  = tid >> 6;
    const int d2 = (tid & 63) * 2;
    const int b   = bid / NKVH;
    const int kvh = bid % NKVH;
    const float* pb = part + (size_t)bid * NSPLIT * PART_STRIDE;

    float M = -1e30f;
    #pragma unroll
    for (int cc = 0; cc < NSPLIT; ++cc)
        M = fmaxf(M, pb[cc * PART_STRIDE + 512 + g]);
    float L = 0.0f, O0 = 0.0f, O1 = 0.0f;
    #pragma unroll
    for (int cc = 0; cc < NSPLIT; ++cc) {
        float mc = pb[cc * PART_STRIDE + 512 + g];
        float sc = __expf(mc - M);                    // empty chunk -> 0
        L  += pb[cc * PART_STRIDE + 516 + g] * sc;
        O0 += pb[cc * PART_STRIDE + g * HD + d2]     * sc;
        O1 += pb[cc * PART_STRIDE + g * HD + d2 + 1] * sc;
    }
    float inv = 1.0f / L;                             // chunk 0 non-empty -> L > 0
    const int h = kvh * NG + g;
    out[((size_t)b * NH + h) * HD + d2]     = O0 * inv;
    out[((size_t)b * NH + h) * HD + d2 + 1] = O1 * inv;
}

extern "C" void kernel_launch(void* const* d_in, const int* in_sizes, int n_in,
                              void* d_out, int out_size, void* d_ws, size_t ws_size,
                              hipStream_t stream)
{
    const float* q   = (const float*)d_in[0];
    const float* kc  = (const float*)d_in[1];
    const float* vc  = (const float*)d_in[2];
    const int*   kvl = (const int*)d_in[3];
    const int*   bt  = (const int*)d_in[4];
    float* part = (float*)d_ws;   // 2048 * 520 * 4 B = 4.26 MB of ws used

    attn_partial_kernel<<<NB * NKVH * NSPLIT, 256, 0, stream>>>(q, kc, vc, kvl, bt, part);
    attn_combine_kernel<<<NB * NKVH, 256, 0, stream>>>(part, (float*)d_out);
}